// Round 8
// baseline (581.365 us; speedup 1.0000x reference)
//
#include <hip/hip_runtime.h>
#include <math.h>

// VQVAE forward — R8: single BARRIER-FREE megakernel. All B-operand fragments
// load directly from L2-resident pre-split weight planes (no LDS staging, no
// __syncthreads). Activations round-trip through wave-private LDS scratch only
// (same-wave lgkmcnt ordering). Histogram via per-row idx stores + separate
// LDS-histogram kernel (R7: removing device atomics cut 300us).
// Precision: fp16 split-2 (hi+lo, 3 MFMA) on encoder+VQ — zero argmin flips
// R4-R7; plain fp16 decoder. absmax stable at 0.015625.

namespace {

constexpr int kN = 262144;

typedef _Float16 half8 __attribute__((ext_vector_type(8)));
typedef float floatx4 __attribute__((ext_vector_type(4)));

#define MFMA16(a, b, c) __builtin_amdgcn_mfma_f32_16x16x32_f16((a), (b), (c), 0, 0, 0)

// ---- workspace byte offsets (weights region)
constexpr size_t W1M_O = 0;        // ew1 padded [256][32] f16 (k>=9 zero), main
constexpr size_t W1R_O = 16384;    // residual
constexpr size_t E2M_O = 32768;    // ew2 [128][256]
constexpr size_t E2R_O = 98304;
constexpr size_t E3M_O = 163840;   // ew3 [64][128]
constexpr size_t E3R_O = 180224;
constexpr size_t CBM_O = 196608;   // codebook [1024][64]
constexpr size_t CBR_O = 327680;
constexpr size_t D1P_O = 458752;   // dw1 [128][64] plain
constexpr size_t D2P_O = 475136;   // dw2 [256][128] plain
constexpr size_t D3P_O = 540672;   // dw3 padded [16][256] plain
constexpr size_t CN_O  = 548864;   // cn [1024] f32
// ---- small outputs
constexpr size_t IDX_O = 589824;             // idx [N] i32 (1 MB)
constexpr size_t ESP_O = IDX_O + 1048576;    // es partials [2048*4] f32
constexpr size_t HP_O  = ESP_O + 32768;      // hist partials [64][1024] i32

__device__ __forceinline__ void split2(float v, _Float16& hi, _Float16& lo) {
  hi = (_Float16)v;
  lo = (_Float16)(v - (float)hi);
}

// =====================================================================
__global__ void prep_kernel(
    const float* __restrict__ ew1, const float* __restrict__ ew2,
    const float* __restrict__ ew3, const float* __restrict__ cb,
    const float* __restrict__ dw1, const float* __restrict__ dw2,
    const float* __restrict__ dw3, char* __restrict__ wsb) {
  _Float16* w1m = (_Float16*)(wsb + W1M_O);
  _Float16* w1r = (_Float16*)(wsb + W1R_O);
  _Float16* e2m = (_Float16*)(wsb + E2M_O);
  _Float16* e2r = (_Float16*)(wsb + E2R_O);
  _Float16* e3m = (_Float16*)(wsb + E3M_O);
  _Float16* e3r = (_Float16*)(wsb + E3R_O);
  _Float16* cbm = (_Float16*)(wsb + CBM_O);
  _Float16* cbr = (_Float16*)(wsb + CBR_O);
  _Float16* d1p = (_Float16*)(wsb + D1P_O);
  _Float16* d2p = (_Float16*)(wsb + D2P_O);
  _Float16* d3p = (_Float16*)(wsb + D3P_O);
  float* cn = (float*)(wsb + CN_O);

  const int gid = blockIdx.x * 256 + threadIdx.x;
  const int stride = gridDim.x * 256;
  for (int e = gid; e < 256 * 32; e += stride) {
    int n = e >> 5, k = e & 31;
    float v = (k < 9) ? ew1[n * 9 + k] : 0.f;
    split2(v, w1m[e], w1r[e]);
  }
  for (int e = gid; e < 128 * 256; e += stride) split2(ew2[e], e2m[e], e2r[e]);
  for (int e = gid; e < 64 * 128; e += stride) split2(ew3[e], e3m[e], e3r[e]);
  for (int e = gid; e < 1024 * 64; e += stride) split2(cb[e], cbm[e], cbr[e]);
  for (int e = gid; e < 128 * 64; e += stride) d1p[e] = (_Float16)dw1[e];
  for (int e = gid; e < 256 * 128; e += stride) d2p[e] = (_Float16)dw2[e];
  for (int e = gid; e < 16 * 256; e += stride) {
    int n = e >> 8, k = e & 255;
    d3p[e] = (n < 9) ? (_Float16)dw3[n * 256 + k] : (_Float16)0.f;
  }
  for (int i = gid; i < 1024; i += stride) {
    float s = 0.f;
    const float* c = cb + (size_t)i * 64;
#pragma unroll 8
    for (int k = 0; k < 64; ++k) s = fmaf(c[k], c[k], s);
    cn[i] = s;
  }
}

// =====================================================================
// Barrier-free megakernel: 128 rows/block, 4 autonomous waves (32 rows each).
__global__ __launch_bounds__(256, 4) void vqvae_mega(
    const float* __restrict__ x,
    const float* __restrict__ eb1, const float* __restrict__ eb2,
    const float* __restrict__ eb3, const float* __restrict__ db1,
    const float* __restrict__ db2, const float* __restrict__ db3,
    const float* __restrict__ cb, const char* __restrict__ wsb,
    float* __restrict__ out, int* __restrict__ idx_g, float* __restrict__ esp_g) {
  __shared__ _Float16 WSC[9216];  // 2304 halfs/wave, wave-private
  __shared__ int Bidx[128];       // rows of this block; same-wave use only

  const int t = threadIdx.x;
  const int lane = t & 63;
  const int w = t >> 6;
  const int m = lane & 15;
  const int q = lane >> 4;
  const int R0 = blockIdx.x * 128;
  const int wr0 = 32 * w;
  _Float16* WPS = WSC + w * 2304;
  const float* cn_g = (const float*)(wsb + CN_O);

  // ---- x fragments (K padded 9->32), per row-tile
  half8 axm[2] = {{}, {}}, axr[2] = {{}, {}};
#pragma unroll
  for (int rt = 0; rt < 2; ++rt) {
    const int grow = R0 + wr0 + 16 * rt + m;
    if (q == 0) {
#pragma unroll
      for (int j = 0; j < 8; ++j) {
        const float v = x[(size_t)grow * 9 + j];
        const _Float16 hi = (_Float16)v;
        axm[rt][j] = hi;
        axr[rt][j] = (_Float16)(v - (float)hi);
      }
    } else if (q == 1) {
      const float v = x[(size_t)grow * 9 + 8];
      const _Float16 hi = (_Float16)v;
      axm[rt][0] = hi;
      axr[rt][0] = (_Float16)(v - (float)hi);
    }
  }

  // ================= Stage A: enc1 fused with enc2; W2 frags direct from L2
  floatx4 acc2[8][2];
#pragma unroll
  for (int nt = 0; nt < 8; ++nt)
#pragma unroll
    for (int rt = 0; rt < 2; ++rt) acc2[nt][rt] = (floatx4){0.f, 0.f, 0.f, 0.f};

  for (int kc = 0; kc < 8; ++kc) {
    // enc1: 32 H1 features this kc -> wave scratch (split planes)
#pragma unroll
    for (int ntl = 0; ntl < 2; ++ntl) {
      const int f = kc * 32 + ntl * 16 + m;
      const half8 bm = *(const half8*)(wsb + W1M_O + (size_t)f * 64 + q * 16);
      const half8 br = *(const half8*)(wsb + W1R_O + (size_t)f * 64 + q * 16);
      const float bias = eb1[f];
#pragma unroll
      for (int rt = 0; rt < 2; ++rt) {
        floatx4 a = (floatx4){0.f, 0.f, 0.f, 0.f};
        a = MFMA16(axr[rt], bm, a);
        a = MFMA16(axm[rt], br, a);
        a = MFMA16(axm[rt], bm, a);
#pragma unroll
        for (int reg = 0; reg < 4; ++reg) {
          const float v = fmaxf(a[reg] + bias, 0.f);
          const int row = 16 * rt + 4 * q + reg;
          const _Float16 hi = (_Float16)v;
          WPS[row * 36 + ntl * 16 + m] = hi;
          WPS[1152 + row * 36 + ntl * 16 + m] = (_Float16)(v - (float)hi);
        }
      }
    }
    half8 am[2], ar[2];
#pragma unroll
    for (int rt = 0; rt < 2; ++rt) {
      am[rt] = *(const half8*)(WPS + (16 * rt + m) * 36 + q * 8);
      ar[rt] = *(const half8*)(WPS + 1152 + (16 * rt + m) * 36 + q * 8);
    }
#pragma unroll
    for (int nt = 0; nt < 8; ++nt) {
      const size_t boff = ((size_t)(nt * 16 + m) * 256 + kc * 32 + q * 8) * 2;
      const half8 bm = *(const half8*)(wsb + E2M_O + boff);
      const half8 br = *(const half8*)(wsb + E2R_O + boff);
#pragma unroll
      for (int rt = 0; rt < 2; ++rt) {
        acc2[nt][rt] = MFMA16(ar[rt], bm, acc2[nt][rt]);
        acc2[nt][rt] = MFMA16(am[rt], br, acc2[nt][rt]);
        acc2[nt][rt] = MFMA16(am[rt], bm, acc2[nt][rt]);
      }
    }
  }

  // ================= Stage B: enc3 (B direct from L2)
  floatx4 acc3[4][2];
#pragma unroll
  for (int nt = 0; nt < 4; ++nt)
#pragma unroll
    for (int rt = 0; rt < 2; ++rt) acc3[nt][rt] = (floatx4){0.f, 0.f, 0.f, 0.f};

  for (int ks = 0; ks < 4; ++ks) {
#pragma unroll
    for (int h = 0; h < 2; ++h) {
      const int nt = 2 * ks + h;
      const float bias = eb2[nt * 16 + m];
#pragma unroll
      for (int rt = 0; rt < 2; ++rt)
#pragma unroll
        for (int reg = 0; reg < 4; ++reg) {
          const float v = fmaxf(acc2[nt][rt][reg] + bias, 0.f);
          const int row = 16 * rt + 4 * q + reg;
          const _Float16 hi = (_Float16)v;
          WPS[row * 36 + h * 16 + m] = hi;
          WPS[1152 + row * 36 + h * 16 + m] = (_Float16)(v - (float)hi);
        }
    }
    half8 am[2], ar[2];
#pragma unroll
    for (int rt = 0; rt < 2; ++rt) {
      am[rt] = *(const half8*)(WPS + (16 * rt + m) * 36 + q * 8);
      ar[rt] = *(const half8*)(WPS + 1152 + (16 * rt + m) * 36 + q * 8);
    }
#pragma unroll
    for (int nt = 0; nt < 4; ++nt) {
      const size_t boff = (size_t)(nt * 16 + m) * 256 + ks * 64 + q * 16;
      const half8 bm = *(const half8*)(wsb + E3M_O + boff);
      const half8 br = *(const half8*)(wsb + E3R_O + boff);
#pragma unroll
      for (int rt = 0; rt < 2; ++rt) {
        acc3[nt][rt] = MFMA16(ar[rt], bm, acc3[nt][rt]);
        acc3[nt][rt] = MFMA16(am[rt], br, acc3[nt][rt]);
        acc3[nt][rt] = MFMA16(am[rt], bm, acc3[nt][rt]);
      }
    }
  }

  // ---- Z epilogue: Z register fragments via wave scratch (argmin needs no ||z||^2)
  half8 zfm[2][2], zfr[2][2];
#pragma unroll
  for (int rt = 0; rt < 2; ++rt) {
#pragma unroll
    for (int nt = 0; nt < 4; ++nt) {
      const float bias = eb3[nt * 16 + m];
#pragma unroll
      for (int reg = 0; reg < 4; ++reg) {
        const float v = acc3[nt][rt][reg] + bias;
        const int row = 4 * q + reg;
        const _Float16 hi = (_Float16)v;
        WPS[row * 72 + nt * 16 + m] = hi;
        WPS[1152 + row * 72 + nt * 16 + m] = (_Float16)(v - (float)hi);
      }
    }
#pragma unroll
    for (int ks2 = 0; ks2 < 2; ++ks2) {
      zfm[rt][ks2] = *(const half8*)(WPS + m * 72 + ks2 * 32 + q * 8);
      zfr[rt][ks2] = *(const half8*)(WPS + 1152 + m * 72 + ks2 * 32 + q * 8);
    }
  }

  // ================= Stage C: VQ argmin over 1024 codes; CB direct from L2
  float bestd[2][4];
  int besti[2][4];
#pragma unroll
  for (int rt = 0; rt < 2; ++rt)
#pragma unroll
    for (int reg = 0; reg < 4; ++reg) { bestd[rt][reg] = 3.4e38f; besti[rt][reg] = 0; }

  for (int cc = 0; cc < 16; ++cc) {
    floatx4 accd[4][2];
#pragma unroll
    for (int nt = 0; nt < 4; ++nt)
#pragma unroll
      for (int rt = 0; rt < 2; ++rt) accd[nt][rt] = (floatx4){0.f, 0.f, 0.f, 0.f};
#pragma unroll
    for (int nt = 0; nt < 4; ++nt) {
#pragma unroll
      for (int ks2 = 0; ks2 < 2; ++ks2) {
        const size_t boff = (size_t)(cc * 64 + nt * 16 + m) * 128 + ks2 * 64 + q * 16;
        const half8 bm = *(const half8*)(wsb + CBM_O + boff);
        const half8 br = *(const half8*)(wsb + CBR_O + boff);
#pragma unroll
        for (int rt = 0; rt < 2; ++rt) {
          accd[nt][rt] = MFMA16(zfr[rt][ks2], bm, accd[nt][rt]);
          accd[nt][rt] = MFMA16(zfm[rt][ks2], br, accd[nt][rt]);
          accd[nt][rt] = MFMA16(zfm[rt][ks2], bm, accd[nt][rt]);
        }
      }
    }
#pragma unroll
    for (int nt = 0; nt < 4; ++nt) {
      const int code = cc * 64 + nt * 16 + m;
      const float cnv = cn_g[code];  // ||z||^2 constant per row -> irrelevant
#pragma unroll
      for (int rt = 0; rt < 2; ++rt) {
#pragma unroll
        for (int reg = 0; reg < 4; ++reg) {
          const float d = cnv - 2.f * accd[nt][rt][reg];
          if (d < bestd[rt][reg]) { bestd[rt][reg] = d; besti[rt][reg] = code; }
        }
      }
    }
  }
#pragma unroll
  for (int rt = 0; rt < 2; ++rt) {
#pragma unroll
    for (int reg = 0; reg < 4; ++reg) {
#pragma unroll
      for (int off = 1; off < 16; off <<= 1) {
        const float od = __shfl_xor(bestd[rt][reg], off, 16);
        const int oi = __shfl_xor(besti[rt][reg], off, 16);
        if (od < bestd[rt][reg] || (od == bestd[rt][reg] && oi < besti[rt][reg])) {
          bestd[rt][reg] = od; besti[rt][reg] = oi;
        }
      }
    }
  }
  if (m == 0) {
#pragma unroll
    for (int rt = 0; rt < 2; ++rt)
#pragma unroll
      for (int reg = 0; reg < 4; ++reg) {
        const int row = wr0 + 16 * rt + 4 * q + reg;
        Bidx[row] = besti[rt][reg];        // same-wave LDS (lgkmcnt ordered)
        idx_g[R0 + row] = besti[rt][reg];  // plain store; hist kernel follows
      }
  }

  // ---- z_q (straight-through, reference rounding) + e_latent partial
  half8 zq[2][2];
  float es = 0.f;
#pragma unroll
  for (int rt = 0; rt < 2; ++rt) {
    const int bi = Bidx[wr0 + 16 * rt + m];
#pragma unroll
    for (int ks2 = 0; ks2 < 2; ++ks2) {
      const float* cp = cb + (size_t)bi * 64 + ks2 * 32 + q * 8;
      const float4 c0 = *(const float4*)cp;
      const float4 c1 = *(const float4*)(cp + 4);
      float cv[8] = {c0.x, c0.y, c0.z, c0.w, c1.x, c1.y, c1.z, c1.w};
#pragma unroll
      for (int j = 0; j < 8; ++j) {
        const float z = (float)zfm[rt][ks2][j] + (float)zfr[rt][ks2][j];
        const float d = cv[j] - z;
        es = fmaf(d, d, es);
        zq[rt][ks2][j] = (_Float16)(z + d);
      }
    }
  }
#pragma unroll
  for (int off = 1; off < 64; off <<= 1) es += __shfl_xor(es, off, 64);
  if (lane == 0) esp_g[blockIdx.x * 4 + w] = es;  // per-wave partial, no atomic

  // ================= Stage D: dec1 (plain fp16, B direct)
  half8 h3f[2][4];
  for (int g = 0; g < 4; ++g) {
#pragma unroll
    for (int h = 0; h < 2; ++h) {
      const int nt = 2 * g + h;
      floatx4 acc[2] = {(floatx4){0.f, 0.f, 0.f, 0.f}, (floatx4){0.f, 0.f, 0.f, 0.f}};
#pragma unroll
      for (int ks2 = 0; ks2 < 2; ++ks2) {
        const half8 b = *(const half8*)(wsb + D1P_O + (size_t)(nt * 16 + m) * 128 + ks2 * 64 + q * 16);
#pragma unroll
        for (int rt = 0; rt < 2; ++rt) acc[rt] = MFMA16(zq[rt][ks2], b, acc[rt]);
      }
      const float bias = db1[nt * 16 + m];
#pragma unroll
      for (int rt = 0; rt < 2; ++rt)
#pragma unroll
        for (int reg = 0; reg < 4; ++reg) {
          const float v = fmaxf(acc[rt][reg] + bias, 0.f);
          WPS[(16 * rt + 4 * q + reg) * 36 + h * 16 + m] = (_Float16)v;
        }
    }
#pragma unroll
    for (int rt = 0; rt < 2; ++rt)
      h3f[rt][g] = *(const half8*)(WPS + (16 * rt + m) * 36 + q * 8);
  }

  // ================= Stage E: dec2 (B direct) fused with dec3
  floatx4 accO[2] = {(floatx4){0.f, 0.f, 0.f, 0.f}, (floatx4){0.f, 0.f, 0.f, 0.f}};
  for (int jc = 0; jc < 4; ++jc) {
    floatx4 accD2[4][2];
#pragma unroll
    for (int nt = 0; nt < 4; ++nt)
#pragma unroll
      for (int rt = 0; rt < 2; ++rt) accD2[nt][rt] = (floatx4){0.f, 0.f, 0.f, 0.f};
#pragma unroll
    for (int nt = 0; nt < 4; ++nt) {
#pragma unroll
      for (int ks = 0; ks < 4; ++ks) {
        const size_t boff = (size_t)(jc * 64 + nt * 16 + m) * 256 + ks * 64 + q * 16;
        const half8 b = *(const half8*)(wsb + D2P_O + boff);
#pragma unroll
        for (int rt = 0; rt < 2; ++rt) accD2[nt][rt] = MFMA16(h3f[rt][ks], b, accD2[nt][rt]);
      }
    }
    half8 b3[2];
#pragma unroll
    for (int ks2 = 0; ks2 < 2; ++ks2)
      b3[ks2] = *(const half8*)(wsb + D3P_O + (size_t)m * 512 + jc * 128 + ks2 * 64 + q * 16);
#pragma unroll
    for (int rt = 0; rt < 2; ++rt) {
#pragma unroll
      for (int nt = 0; nt < 4; ++nt) {
        const float bias = db2[jc * 64 + nt * 16 + m];
#pragma unroll
        for (int reg = 0; reg < 4; ++reg) {
          const float v = fmaxf(accD2[nt][rt][reg] + bias, 0.f);
          WPS[(4 * q + reg) * 72 + nt * 16 + m] = (_Float16)v;
        }
      }
#pragma unroll
      for (int ks2 = 0; ks2 < 2; ++ks2) {
        const half8 am = *(const half8*)(WPS + m * 72 + ks2 * 32 + q * 8);
        accO[rt] = MFMA16(am, b3[ks2], accO[rt]);
      }
    }
  }
  if (m < 9) {
    const float bias = db3[m];
#pragma unroll
    for (int rt = 0; rt < 2; ++rt)
#pragma unroll
      for (int reg = 0; reg < 4; ++reg) {
        const size_t r = (size_t)(R0 + wr0 + 16 * rt + 4 * q + reg);
        out[r * 9 + m] = accO[rt][reg] + bias;
      }
  }
}

// =====================================================================
// hist: 64 blocks x 256 thr; LDS histogram over idx -> partials.
__global__ __launch_bounds__(256) void hist_kernel(
    const int* __restrict__ idx_g, int* __restrict__ hp) {
  __shared__ int lh[1024];
  const int t = threadIdx.x;
#pragma unroll
  for (int i = 0; i < 4; ++i) lh[t * 4 + i] = 0;
  __syncthreads();
  for (int i = t; i < 4096; i += 256)
    atomicAdd(&lh[idx_g[blockIdx.x * 4096 + i]], 1);  // LDS atomic only
  __syncthreads();
  int* part = hp + blockIdx.x * 1024;
#pragma unroll
  for (int i = 0; i < 4; ++i) part[t * 4 + i] = lh[t * 4 + i];
}

// =====================================================================
__global__ __launch_bounds__(1024) void finalize_kernel(
    const int* __restrict__ hp, const float* __restrict__ esp,
    float* __restrict__ out2) {
  __shared__ double red[1024];
  __shared__ float rede[1024];
  const int t = threadIdx.x;
  int h = 0;
#pragma unroll 8
  for (int p = 0; p < 64; ++p) h += hp[p * 1024 + t];
  const float pr = (float)h * (1.0f / (float)kN);
  red[t] = (double)(pr * logf(pr + 1e-10f));
  float es = 0.f;
#pragma unroll
  for (int i = 0; i < 8; ++i) es += esp[i * 1024 + t];
  rede[t] = es;
  __syncthreads();
  for (int s = 512; s > 0; s >>= 1) {
    if (t < s) { red[t] += red[t + s]; rede[t] += rede[t + s]; }
    __syncthreads();
  }
  if (t == 0) {
    out2[0] = 1.25f * (rede[0] * (1.0f / ((float)kN * 64.0f)));
    out2[1] = expf((float)(-red[0]));
  }
}

}  // namespace

extern "C" void kernel_launch(void* const* d_in, const int* in_sizes, int n_in,
                              void* d_out, int out_size, void* d_ws, size_t ws_size,
                              hipStream_t stream) {
  const float* x   = (const float*)d_in[0];
  const float* ew1 = (const float*)d_in[1];
  const float* eb1 = (const float*)d_in[2];
  const float* ew2 = (const float*)d_in[3];
  const float* eb2 = (const float*)d_in[4];
  const float* ew3 = (const float*)d_in[5];
  const float* eb3 = (const float*)d_in[6];
  const float* dw1 = (const float*)d_in[7];
  const float* db1 = (const float*)d_in[8];
  const float* dw2 = (const float*)d_in[9];
  const float* db2 = (const float*)d_in[10];
  const float* dw3 = (const float*)d_in[11];
  const float* db3 = (const float*)d_in[12];
  const float* cb  = (const float*)d_in[13];
  float* out = (float*)d_out;
  char* wsb = (char*)d_ws;

  int* idx_g = (int*)(wsb + IDX_O);
  float* esp = (float*)(wsb + ESP_O);
  int* hp = (int*)(wsb + HP_O);

  prep_kernel<<<128, 256, 0, stream>>>(ew1, ew2, ew3, cb, dw1, dw2, dw3, wsb);
  vqvae_mega<<<kN / 128, 256, 0, stream>>>(x, eb1, eb2, eb3, db1, db2, db3, cb,
                                           wsb, out, idx_g, esp);
  hist_kernel<<<64, 256, 0, stream>>>(idx_g, hp);
  finalize_kernel<<<1, 1024, 0, stream>>>(hp, esp, out + (size_t)kN * 9);
}

// Round 9
// 475.701 us; speedup vs baseline: 1.2221x; 1.2221x over previous
//
#include <hip/hip_runtime.h>
#include <math.h>

// VQVAE forward — R9: R7 3-kernel split (champion, 406us) with DOUBLE-BUFFERED
// staging in enc and vq (one barrier per chunk; prefetch overlaps MFMA).
// R8 lesson: per-wave direct B loads (no staging) regressed to 581us — staging
// amortization across the block's waves is essential; only barrier count and
// latency exposure should be cut.
// Precision: fp16 split-2 (hi+lo, 3 MFMA) on encoder+VQ — zero argmin flips
// R4-R8 (absmax stable 0.015625 = decoder fp16 rounding); plain fp16 decoder.
// No device-scope atomics (R7: removing them cut 300us).

namespace {

constexpr int kN = 262144;

typedef _Float16 half8 __attribute__((ext_vector_type(8)));
typedef float floatx4 __attribute__((ext_vector_type(4)));

#define MFMA16(a, b, c) __builtin_amdgcn_mfma_f32_16x16x32_f16((a), (b), (c), 0, 0, 0)

// ---- workspace byte offsets (weights region)
constexpr size_t W1M_O = 0;        // ew1 padded [256][32] f16 (k>=9 zero), main
constexpr size_t W1R_O = 16384;    // residual
constexpr size_t E2M_O = 32768;    // ew2 [128][256]
constexpr size_t E2R_O = 98304;
constexpr size_t E3M_O = 163840;   // ew3 [64][128]
constexpr size_t E3R_O = 180224;
constexpr size_t CBM_O = 196608;   // codebook [1024][64]
constexpr size_t CBR_O = 327680;
constexpr size_t D1P_O = 458752;   // dw1 [128][64] plain
constexpr size_t D2P_O = 475136;   // dw2 [256][128] plain
constexpr size_t D3P_O = 540672;   // dw3 padded [16][256] plain
constexpr size_t CN_O  = 548864;   // cn [1024] f32
// ---- intermediates. Fragment-major: half off = rowblk*1024 + s*128 + m*8 + j.
constexpr size_t ZFM_O = 589824;                  // z main plane [N*64] f16
constexpr size_t ZFR_O = ZFM_O + 33554432;        // z resid plane
constexpr size_t ZQF_O = ZFR_O + 33554432;        // zq plain f16
// Dead-region reuse (proven R7; needs no ws beyond ZQF end):
//  - vq block b scratch at ZFM_O + b*16384: idx[128] i32 + es f32 @+512
//  - hist partials: 64 x 1024 i32 @ ZFR_O

__device__ __forceinline__ void split2(float v, _Float16& hi, _Float16& lo) {
  hi = (_Float16)v;
  lo = (_Float16)(v - (float)hi);
}

// =====================================================================
__global__ void prep_kernel(
    const float* __restrict__ ew1, const float* __restrict__ ew2,
    const float* __restrict__ ew3, const float* __restrict__ cb,
    const float* __restrict__ dw1, const float* __restrict__ dw2,
    const float* __restrict__ dw3, char* __restrict__ wsb) {
  _Float16* w1m = (_Float16*)(wsb + W1M_O);
  _Float16* w1r = (_Float16*)(wsb + W1R_O);
  _Float16* e2m = (_Float16*)(wsb + E2M_O);
  _Float16* e2r = (_Float16*)(wsb + E2R_O);
  _Float16* e3m = (_Float16*)(wsb + E3M_O);
  _Float16* e3r = (_Float16*)(wsb + E3R_O);
  _Float16* cbm = (_Float16*)(wsb + CBM_O);
  _Float16* cbr = (_Float16*)(wsb + CBR_O);
  _Float16* d1p = (_Float16*)(wsb + D1P_O);
  _Float16* d2p = (_Float16*)(wsb + D2P_O);
  _Float16* d3p = (_Float16*)(wsb + D3P_O);
  float* cn = (float*)(wsb + CN_O);

  const int gid = blockIdx.x * 256 + threadIdx.x;
  const int stride = gridDim.x * 256;
  for (int e = gid; e < 256 * 32; e += stride) {
    int n = e >> 5, k = e & 31;
    float v = (k < 9) ? ew1[n * 9 + k] : 0.f;
    split2(v, w1m[e], w1r[e]);
  }
  for (int e = gid; e < 128 * 256; e += stride) split2(ew2[e], e2m[e], e2r[e]);
  for (int e = gid; e < 64 * 128; e += stride) split2(ew3[e], e3m[e], e3r[e]);
  for (int e = gid; e < 1024 * 64; e += stride) split2(cb[e], cbm[e], cbr[e]);
  for (int e = gid; e < 128 * 64; e += stride) d1p[e] = (_Float16)dw1[e];
  for (int e = gid; e < 256 * 128; e += stride) d2p[e] = (_Float16)dw2[e];
  for (int e = gid; e < 16 * 256; e += stride) {
    int n = e >> 8, k = e & 255;
    d3p[e] = (n < 9) ? (_Float16)dw3[n * 256 + k] : (_Float16)0.f;
  }
  for (int i = gid; i < 1024; i += stride) {
    float s = 0.f;
    const float* c = cb + (size_t)i * 64;
#pragma unroll 8
    for (int k = 0; k < 64; ++k) s = fmaf(c[k], c[k], s);
    cn[i] = s;
  }
}

// =====================================================================
// enc: x -> Z split planes. 128 rows/block, 4 waves, rt=2. Double-buffered W2.
__global__ __launch_bounds__(256, 2) void enc_kernel(
    const float* __restrict__ x,
    const float* __restrict__ eb1, const float* __restrict__ eb2,
    const float* __restrict__ eb3, char* __restrict__ wsb) {
  // LDS: W2 stage dbuf 2 x ([128][36] x 2 planes = 9216) @0..18432;
  // wave scratch 2304 halfs/wave @ 18432 + w*2304
  __shared__ _Float16 LP[27648];

  const int t = threadIdx.x;
  const int w = t >> 6;
  const int lane = t & 63;
  const int m = lane & 15;
  const int q = lane >> 4;
  const int R0 = blockIdx.x * 128;
  _Float16* WPS = LP + 18432 + w * 2304;

  // staging role of this thread: plane sp (0=main,1=resid), row sn
  const int sp = t >> 7, sn = t & 127;
  const size_t eSrc = (sp ? E2R_O : E2M_O) + (size_t)sn * 512;

  // x fragments (K padded 9->32), per row-tile
  half8 axm[2] = {{}, {}}, axr[2] = {{}, {}};
#pragma unroll
  for (int rt = 0; rt < 2; ++rt) {
    const int grow = R0 + 32 * w + 16 * rt + m;
    if (q == 0) {
#pragma unroll
      for (int j = 0; j < 8; ++j) {
        const float v = x[(size_t)grow * 9 + j];
        const _Float16 hi = (_Float16)v;
        axm[rt][j] = hi;
        axr[rt][j] = (_Float16)(v - (float)hi);
      }
    } else if (q == 1) {
      const float v = x[(size_t)grow * 9 + 8];
      const _Float16 hi = (_Float16)v;
      axm[rt][0] = hi;
      axr[rt][0] = (_Float16)(v - (float)hi);
    }
  }

  // preload chunk 0 into buffer 0
  {
    const char* src = wsb + eSrc;
    _Float16* dst = LP + sp * 4608 + sn * 36;
#pragma unroll
    for (int j = 0; j < 4; ++j)
      *(half8*)(dst + j * 8) = *(const half8*)(src + j * 16);
  }
  __syncthreads();

  // Stage A: enc1 fused with enc2, double-buffered W2 chunks
  floatx4 acc2[8][2];
#pragma unroll
  for (int nt = 0; nt < 8; ++nt)
#pragma unroll
    for (int rt = 0; rt < 2; ++rt) acc2[nt][rt] = (floatx4){0.f, 0.f, 0.f, 0.f};

  for (int kc = 0; kc < 8; ++kc) {
    const _Float16* cur = LP + (kc & 1) * 9216;
    half8 pre[4];
    if (kc < 7) {  // issue prefetch loads for chunk kc+1 (wait absorbed below)
      const char* src = wsb + eSrc + (kc + 1) * 64;
#pragma unroll
      for (int j = 0; j < 4; ++j) pre[j] = *(const half8*)(src + j * 16);
    }
    // enc1: 32 H1 features this kc (independent of staged data — overlaps loads)
#pragma unroll
    for (int ntl = 0; ntl < 2; ++ntl) {
      const int f = kc * 32 + ntl * 16 + m;
      const half8 bm = *(const half8*)(wsb + W1M_O + (size_t)f * 64 + q * 16);
      const half8 br = *(const half8*)(wsb + W1R_O + (size_t)f * 64 + q * 16);
      const float bias = eb1[f];
#pragma unroll
      for (int rt = 0; rt < 2; ++rt) {
        floatx4 a = (floatx4){0.f, 0.f, 0.f, 0.f};
        a = MFMA16(axr[rt], bm, a);
        a = MFMA16(axm[rt], br, a);
        a = MFMA16(axm[rt], bm, a);
#pragma unroll
        for (int reg = 0; reg < 4; ++reg) {
          const float v = fmaxf(a[reg] + bias, 0.f);
          const int row = 16 * rt + 4 * q + reg;
          const _Float16 hi = (_Float16)v;
          WPS[row * 36 + ntl * 16 + m] = hi;
          WPS[1152 + row * 36 + ntl * 16 + m] = (_Float16)(v - (float)hi);
        }
      }
    }
    half8 am[2], ar[2];
#pragma unroll
    for (int rt = 0; rt < 2; ++rt) {
      am[rt] = *(const half8*)(WPS + (16 * rt + m) * 36 + q * 8);
      ar[rt] = *(const half8*)(WPS + 1152 + (16 * rt + m) * 36 + q * 8);
    }
    // enc2: one K-step of 32 from current staged buffer
#pragma unroll
    for (int nt = 0; nt < 8; ++nt) {
      const half8 bm = *(const half8*)(cur + (nt * 16 + m) * 36 + q * 8);
      const half8 br = *(const half8*)(cur + 4608 + (nt * 16 + m) * 36 + q * 8);
#pragma unroll
      for (int rt = 0; rt < 2; ++rt) {
        acc2[nt][rt] = MFMA16(ar[rt], bm, acc2[nt][rt]);
        acc2[nt][rt] = MFMA16(am[rt], br, acc2[nt][rt]);
        acc2[nt][rt] = MFMA16(am[rt], bm, acc2[nt][rt]);
      }
    }
    if (kc < 7) {  // publish prefetched chunk into the other buffer
      _Float16* dst = LP + ((kc + 1) & 1) * 9216 + sp * 4608 + sn * 36;
#pragma unroll
      for (int j = 0; j < 4; ++j) *(half8*)(dst + j * 8) = pre[j];
      __syncthreads();  // single barrier per kc
    }
  }

  // Stage B: enc3 (K=128 in 4 steps; H2 via wave scratch; B direct from L2)
  floatx4 acc3[4][2];
#pragma unroll
  for (int nt = 0; nt < 4; ++nt)
#pragma unroll
    for (int rt = 0; rt < 2; ++rt) acc3[nt][rt] = (floatx4){0.f, 0.f, 0.f, 0.f};

  for (int ks = 0; ks < 4; ++ks) {
#pragma unroll
    for (int h = 0; h < 2; ++h) {
      const int nt = 2 * ks + h;
      const float bias = eb2[nt * 16 + m];
#pragma unroll
      for (int rt = 0; rt < 2; ++rt)
#pragma unroll
        for (int reg = 0; reg < 4; ++reg) {
          const float v = fmaxf(acc2[nt][rt][reg] + bias, 0.f);
          const int row = 16 * rt + 4 * q + reg;
          const _Float16 hi = (_Float16)v;
          WPS[row * 36 + h * 16 + m] = hi;
          WPS[1152 + row * 36 + h * 16 + m] = (_Float16)(v - (float)hi);
        }
    }
    half8 am[2], ar[2];
#pragma unroll
    for (int rt = 0; rt < 2; ++rt) {
      am[rt] = *(const half8*)(WPS + (16 * rt + m) * 36 + q * 8);
      ar[rt] = *(const half8*)(WPS + 1152 + (16 * rt + m) * 36 + q * 8);
    }
#pragma unroll
    for (int nt = 0; nt < 4; ++nt) {
      const half8 bm = *(const half8*)(wsb + E3M_O + (size_t)(nt * 16 + m) * 256 + ks * 64 + q * 16);
      const half8 br = *(const half8*)(wsb + E3R_O + (size_t)(nt * 16 + m) * 256 + ks * 64 + q * 16);
#pragma unroll
      for (int rt = 0; rt < 2; ++rt) {
        acc3[nt][rt] = MFMA16(ar[rt], bm, acc3[nt][rt]);
        acc3[nt][rt] = MFMA16(am[rt], br, acc3[nt][rt]);
        acc3[nt][rt] = MFMA16(am[rt], bm, acc3[nt][rt]);
      }
    }
  }

  // Z epilogue: split planes via wave scratch -> fragment-major global
  _Float16* zm_g = (_Float16*)(wsb + ZFM_O);
  _Float16* zr_g = (_Float16*)(wsb + ZFR_O);
#pragma unroll
  for (int rt = 0; rt < 2; ++rt) {
#pragma unroll
    for (int nt = 0; nt < 4; ++nt) {
      const float bias = eb3[nt * 16 + m];
#pragma unroll
      for (int reg = 0; reg < 4; ++reg) {
        const float v = acc3[nt][rt][reg] + bias;
        const int row = 4 * q + reg;
        const _Float16 hi = (_Float16)v;
        WPS[row * 72 + nt * 16 + m] = hi;
        WPS[1152 + row * 72 + nt * 16 + m] = (_Float16)(v - (float)hi);
      }
    }
    const size_t b = (size_t)blockIdx.x * 8 + w * 2 + rt;
#pragma unroll
    for (int ks2 = 0; ks2 < 2; ++ks2) {
      const half8 zm = *(const half8*)(WPS + m * 72 + ks2 * 32 + q * 8);
      const half8 zr = *(const half8*)(WPS + 1152 + m * 72 + ks2 * 32 + q * 8);
      const size_t off = b * 1024 + (ks2 * 4 + q) * 128 + m * 8;
      *(half8*)(zm_g + off) = zm;
      *(half8*)(zr_g + off) = zr;
    }
  }
}

// =====================================================================
// vq: Z frags -> argmin -> zq frags + per-row idx + per-block es. Dbuf CB.
__global__ __launch_bounds__(256, 4) void vq_kernel(
    char* __restrict__ wsb, const float* __restrict__ cb) {
  __shared__ _Float16 LP[18432];  // dbuf 2 x ([64][72] x 2 planes = 9216)
  __shared__ int Bidx[128];
  __shared__ float ESL[4];

  const int t = threadIdx.x;
  const int lane = t & 63;
  const int w = t >> 6;
  const int m = lane & 15;
  const int q = lane >> 4;
  const int wr0 = 32 * w;
  const float* cn_g = (const float*)(wsb + CN_O);
  const _Float16* zm_g = (const _Float16*)(wsb + ZFM_O);
  const _Float16* zr_g = (const _Float16*)(wsb + ZFR_O);
  _Float16* zq_g = (_Float16*)(wsb + ZQF_O);
  int* idx_p = (int*)(wsb + ZFM_O + (size_t)blockIdx.x * 16384);
  float* es_p = (float*)(wsb + ZFM_O + (size_t)blockIdx.x * 16384 + 512);

  // staging role: plane sp, row sn (0..63), half hh
  const int sp = t >> 7, se = t & 127;
  const int sn = se >> 1, hh = se & 1;
  const size_t cSrc = (sp ? CBR_O : CBM_O) + (size_t)sn * 128 + hh * 64;
  const int sDst = sp * 4608 + sn * 72 + hh * 32;

  // Z fragments straight from global (fragment-major, coalesced)
  half8 zfm[2][2], zfr[2][2];
#pragma unroll
  for (int rt = 0; rt < 2; ++rt) {
    const size_t b = (size_t)blockIdx.x * 8 + w * 2 + rt;
#pragma unroll
    for (int ks2 = 0; ks2 < 2; ++ks2) {
      const size_t off = b * 1024 + (ks2 * 4 + q) * 128 + m * 8;
      zfm[rt][ks2] = *(const half8*)(zm_g + off);
      zfr[rt][ks2] = *(const half8*)(zr_g + off);
    }
  }

  // preload codebook chunk 0
  {
    const char* src = wsb + cSrc;
    _Float16* dst = LP + sDst;
#pragma unroll
    for (int j = 0; j < 4; ++j)
      *(half8*)(dst + j * 8) = *(const half8*)(src + j * 16);
  }
  __syncthreads();

  float bestd[2][4];
  int besti[2][4];
#pragma unroll
  for (int rt = 0; rt < 2; ++rt)
#pragma unroll
    for (int reg = 0; reg < 4; ++reg) { bestd[rt][reg] = 3.4e38f; besti[rt][reg] = 0; }

  for (int cc = 0; cc < 16; ++cc) {
    const _Float16* cur = LP + (cc & 1) * 9216;
    half8 pre[4];
    if (cc < 15) {
      const char* src = wsb + cSrc + (size_t)(cc + 1) * 64 * 128;
#pragma unroll
      for (int j = 0; j < 4; ++j) pre[j] = *(const half8*)(src + j * 16);
    }
    floatx4 accd[4][2];
#pragma unroll
    for (int nt = 0; nt < 4; ++nt)
#pragma unroll
      for (int rt = 0; rt < 2; ++rt) accd[nt][rt] = (floatx4){0.f, 0.f, 0.f, 0.f};
#pragma unroll
    for (int nt = 0; nt < 4; ++nt) {
#pragma unroll
      for (int ks2 = 0; ks2 < 2; ++ks2) {
        const half8 bm = *(const half8*)(cur + (nt * 16 + m) * 72 + ks2 * 32 + q * 8);
        const half8 br = *(const half8*)(cur + 4608 + (nt * 16 + m) * 72 + ks2 * 32 + q * 8);
#pragma unroll
        for (int rt = 0; rt < 2; ++rt) {
          accd[nt][rt] = MFMA16(zfr[rt][ks2], bm, accd[nt][rt]);
          accd[nt][rt] = MFMA16(zfm[rt][ks2], br, accd[nt][rt]);
          accd[nt][rt] = MFMA16(zfm[rt][ks2], bm, accd[nt][rt]);
        }
      }
    }
#pragma unroll
    for (int nt = 0; nt < 4; ++nt) {
      const int code = cc * 64 + nt * 16 + m;
      const float cnv = cn_g[code];  // ||z||^2 constant per row -> irrelevant
#pragma unroll
      for (int rt = 0; rt < 2; ++rt) {
#pragma unroll
        for (int reg = 0; reg < 4; ++reg) {
          const float d = cnv - 2.f * accd[nt][rt][reg];
          if (d < bestd[rt][reg]) { bestd[rt][reg] = d; besti[rt][reg] = code; }
        }
      }
    }
    if (cc < 15) {
      _Float16* dst = LP + ((cc + 1) & 1) * 9216 + sDst;
#pragma unroll
      for (int j = 0; j < 4; ++j) *(half8*)(dst + j * 8) = pre[j];
      __syncthreads();  // single barrier per cc
    }
  }
#pragma unroll
  for (int rt = 0; rt < 2; ++rt) {
#pragma unroll
    for (int reg = 0; reg < 4; ++reg) {
#pragma unroll
      for (int off = 1; off < 16; off <<= 1) {
        const float od = __shfl_xor(bestd[rt][reg], off, 16);
        const int oi = __shfl_xor(besti[rt][reg], off, 16);
        if (od < bestd[rt][reg] || (od == bestd[rt][reg] && oi < besti[rt][reg])) {
          bestd[rt][reg] = od; besti[rt][reg] = oi;
        }
      }
    }
  }
  if (m == 0) {
#pragma unroll
    for (int rt = 0; rt < 2; ++rt)
#pragma unroll
      for (int reg = 0; reg < 4; ++reg) {
        const int row = wr0 + 16 * rt + 4 * q + reg;
        Bidx[row] = besti[rt][reg];   // same-wave LDS use only
        idx_p[row] = besti[rt][reg];  // plain store (own dead ZFM slice)
      }
  }
  // z_q (straight-through, reference rounding) + e_latent partial
  float es = 0.f;
#pragma unroll
  for (int rt = 0; rt < 2; ++rt) {
    const int bi = Bidx[wr0 + 16 * rt + m];
    const size_t b = (size_t)blockIdx.x * 8 + w * 2 + rt;
#pragma unroll
    for (int ks2 = 0; ks2 < 2; ++ks2) {
      const float* cp = cb + (size_t)bi * 64 + ks2 * 32 + q * 8;
      const float4 c0 = *(const float4*)cp;
      const float4 c1 = *(const float4*)(cp + 4);
      float cv[8] = {c0.x, c0.y, c0.z, c0.w, c1.x, c1.y, c1.z, c1.w};
      half8 zq;
#pragma unroll
      for (int j = 0; j < 8; ++j) {
        const float z = (float)zfm[rt][ks2][j] + (float)zfr[rt][ks2][j];
        const float d = cv[j] - z;
        es = fmaf(d, d, es);
        zq[j] = (_Float16)(z + d);
      }
      *(half8*)(zq_g + b * 1024 + (ks2 * 4 + q) * 128 + m * 8) = zq;
    }
  }
#pragma unroll
  for (int off = 1; off < 64; off <<= 1) es += __shfl_xor(es, off, 64);
  if (lane == 0) ESL[w] = es;
  __syncthreads();
  if (t == 0) *es_p = ESL[0] + ESL[1] + ESL[2] + ESL[3];
}

// =====================================================================
// hist: 64 blocks x 256 thr; LDS histogram over idx, partials into ZFR region.
__global__ __launch_bounds__(256) void hist_kernel(char* __restrict__ wsb) {
  __shared__ int lh[1024];
  const int t = threadIdx.x;
#pragma unroll
  for (int i = 0; i < 4; ++i) lh[t * 4 + i] = 0;
  __syncthreads();
  const char* base = wsb + ZFM_O;
  for (int i = t; i < 4096; i += 256) {
    const int r = blockIdx.x * 4096 + i;
    const int idx = *(const int*)(base + (size_t)(r >> 7) * 16384 + (r & 127) * 4);
    atomicAdd(&lh[idx], 1);  // LDS atomic only
  }
  __syncthreads();
  int* part = (int*)(wsb + ZFR_O) + blockIdx.x * 1024;
#pragma unroll
  for (int i = 0; i < 4; ++i) part[t * 4 + i] = lh[t * 4 + i];
}

// =====================================================================
__global__ __launch_bounds__(1024) void finalize3_kernel(
    const char* __restrict__ wsb, float* __restrict__ out2) {
  __shared__ double red[1024];
  __shared__ float rede[1024];
  const int t = threadIdx.x;
  const int* part = (const int*)(wsb + ZFR_O);
  int h = 0;
#pragma unroll 8
  for (int p = 0; p < 64; ++p) h += part[p * 1024 + t];
  const float pr = (float)h * (1.0f / (float)kN);
  red[t] = (double)(pr * logf(pr + 1e-10f));
  const char* scr = wsb + ZFM_O;
  float es = *(const float*)(scr + (size_t)t * 16384 + 512) +
             *(const float*)(scr + (size_t)(t + 1024) * 16384 + 512);
  rede[t] = es;
  __syncthreads();
  for (int s = 512; s > 0; s >>= 1) {
    if (t < s) { red[t] += red[t + s]; rede[t] += rede[t + s]; }
    __syncthreads();
  }
  if (t == 0) {
    out2[0] = 1.25f * (rede[0] * (1.0f / ((float)kN * 64.0f)));
    out2[1] = expf((float)(-red[0]));
  }
}

// =====================================================================
// dec: zq frags -> x_recon. (unchanged from R7)
__global__ __launch_bounds__(256, 4) void dec_kernel(
    const float* __restrict__ db1, const float* __restrict__ db2,
    const float* __restrict__ db3, const char* __restrict__ wsb,
    float* __restrict__ out) {
  __shared__ _Float16 LP[13312];

  const int t = threadIdx.x;
  const int lane = t & 63;
  const int w = t >> 6;
  const int m = lane & 15;
  const int q = lane >> 4;
  const int R0 = blockIdx.x * 128;
  _Float16* WPS = LP + 8704 + w * 1152;
  const _Float16* zq_g = (const _Float16*)(wsb + ZQF_O);

  half8 zq[2][2];
#pragma unroll
  for (int rt = 0; rt < 2; ++rt) {
    const size_t b = (size_t)blockIdx.x * 8 + w * 2 + rt;
#pragma unroll
    for (int ks2 = 0; ks2 < 2; ++ks2)
      zq[rt][ks2] = *(const half8*)(zq_g + b * 1024 + (ks2 * 4 + q) * 128 + m * 8);
  }

  half8 h3f[2][4];
  for (int g = 0; g < 4; ++g) {
#pragma unroll
    for (int h = 0; h < 2; ++h) {
      const int nt = 2 * g + h;
      floatx4 acc[2] = {(floatx4){0.f, 0.f, 0.f, 0.f}, (floatx4){0.f, 0.f, 0.f, 0.f}};
#pragma unroll
      for (int ks2 = 0; ks2 < 2; ++ks2) {
        const half8 bfr = *(const half8*)(wsb + D1P_O + (size_t)(nt * 16 + m) * 128 + ks2 * 64 + q * 16);
#pragma unroll
        for (int rt = 0; rt < 2; ++rt) acc[rt] = MFMA16(zq[rt][ks2], bfr, acc[rt]);
      }
      const float bias = db1[nt * 16 + m];
#pragma unroll
      for (int rt = 0; rt < 2; ++rt)
#pragma unroll
        for (int reg = 0; reg < 4; ++reg) {
          const float v = fmaxf(acc[rt][reg] + bias, 0.f);
          WPS[(16 * rt + 4 * q + reg) * 36 + h * 16 + m] = (_Float16)v;
        }
    }
#pragma unroll
    for (int rt = 0; rt < 2; ++rt)
      h3f[rt][g] = *(const half8*)(WPS + (16 * rt + m) * 36 + q * 8);
  }

  floatx4 accO[2] = {(floatx4){0.f, 0.f, 0.f, 0.f}, (floatx4){0.f, 0.f, 0.f, 0.f}};
  for (int jc = 0; jc < 4; ++jc) {
    __syncthreads();
    {
      const int n = t >> 2, jj = t & 3;
      const char* src = wsb + D2P_O + (size_t)(jc * 64 + n) * 256 + jj * 64;
      _Float16* dst = LP + n * 136 + jj * 32;
#pragma unroll
      for (int j = 0; j < 4; ++j)
        *(half8*)(dst + j * 8) = *(const half8*)(src + j * 16);
    }
    __syncthreads();
    floatx4 accD2[4][2];
#pragma unroll
    for (int nt = 0; nt < 4; ++nt)
#pragma unroll
      for (int rt = 0; rt < 2; ++rt) accD2[nt][rt] = (floatx4){0.f, 0.f, 0.f, 0.f};
#pragma unroll
    for (int nt = 0; nt < 4; ++nt) {
#pragma unroll
      for (int ks = 0; ks < 4; ++ks) {
        const half8 bfr = *(const half8*)(LP + (nt * 16 + m) * 136 + ks * 32 + q * 8);
#pragma unroll
        for (int rt = 0; rt < 2; ++rt) accD2[nt][rt] = MFMA16(h3f[rt][ks], bfr, accD2[nt][rt]);
      }
    }
    half8 b3[2];
#pragma unroll
    for (int ks2 = 0; ks2 < 2; ++ks2)
      b3[ks2] = *(const half8*)(wsb + D3P_O + (size_t)m * 512 + jc * 128 + ks2 * 64 + q * 16);
#pragma unroll
    for (int rt = 0; rt < 2; ++rt) {
#pragma unroll
      for (int nt = 0; nt < 4; ++nt) {
        const float bias = db2[jc * 64 + nt * 16 + m];
#pragma unroll
        for (int reg = 0; reg < 4; ++reg) {
          const float v = fmaxf(accD2[nt][rt][reg] + bias, 0.f);
          WPS[(4 * q + reg) * 72 + nt * 16 + m] = (_Float16)v;
        }
      }
#pragma unroll
      for (int ks2 = 0; ks2 < 2; ++ks2) {
        const half8 am = *(const half8*)(WPS + m * 72 + ks2 * 32 + q * 8);
        accO[rt] = MFMA16(am, b3[ks2], accO[rt]);
      }
    }
  }
  if (m < 9) {
    const float bias = db3[m];
#pragma unroll
    for (int rt = 0; rt < 2; ++rt)
#pragma unroll
      for (int reg = 0; reg < 4; ++reg) {
        const size_t r = (size_t)(R0 + 32 * w + 16 * rt + 4 * q + reg);
        out[r * 9 + m] = accO[rt][reg] + bias;
      }
  }
}

}  // namespace

extern "C" void kernel_launch(void* const* d_in, const int* in_sizes, int n_in,
                              void* d_out, int out_size, void* d_ws, size_t ws_size,
                              hipStream_t stream) {
  const float* x   = (const float*)d_in[0];
  const float* ew1 = (const float*)d_in[1];
  const float* eb1 = (const float*)d_in[2];
  const float* ew2 = (const float*)d_in[3];
  const float* eb2 = (const float*)d_in[4];
  const float* ew3 = (const float*)d_in[5];
  const float* eb3 = (const float*)d_in[6];
  const float* dw1 = (const float*)d_in[7];
  const float* db1 = (const float*)d_in[8];
  const float* dw2 = (const float*)d_in[9];
  const float* db2 = (const float*)d_in[10];
  const float* dw3 = (const float*)d_in[11];
  const float* db3 = (const float*)d_in[12];
  const float* cb  = (const float*)d_in[13];
  float* out = (float*)d_out;
  char* wsb = (char*)d_ws;

  prep_kernel<<<128, 256, 0, stream>>>(ew1, ew2, ew3, cb, dw1, dw2, dw3, wsb);
  enc_kernel<<<kN / 128, 256, 0, stream>>>(x, eb1, eb2, eb3, wsb);
  vq_kernel<<<kN / 128, 256, 0, stream>>>(wsb, cb);
  hist_kernel<<<64, 256, 0, stream>>>(wsb);
  dec_kernel<<<kN / 128, 256, 0, stream>>>(db1, db2, db3, wsb, out);
  finalize3_kernel<<<1, 1024, 0, stream>>>(wsb, out + (size_t)kN * 9);
}

// Round 10
// 327.937 us; speedup vs baseline: 1.7728x; 1.4506x over previous
//
#include <hip/hip_runtime.h>
#include <math.h>

// VQVAE forward — R10: R5's shared-staging megakernel (128 rows/block, LDS
// staging for W2/CB/WD2, 3 blocks/CU) WITH the R7 no-atomic treatment:
// per-row idx plain stores + per-wave es partials + separate LDS-histogram
// kernel. Rationale: R5's 436us was measured AT the ~450us device-atomic
// floor (R6: floor is occupancy-independent); its compute structure was never
// seen unmasked. R8 (no staging) and R9 (dbuf, 2 blk/CU) both proved staging
// amortization + cross-block TLP are the binding resources — R5 has both.
// Precision: fp16 split-2 enc+VQ (zero argmin flips R4-R9), plain fp16 dec.

namespace {

constexpr int kN = 262144;

typedef _Float16 half8 __attribute__((ext_vector_type(8)));
typedef float floatx4 __attribute__((ext_vector_type(4)));

#define MFMA16(a, b, c) __builtin_amdgcn_mfma_f32_16x16x32_f16((a), (b), (c), 0, 0, 0)

// ---- workspace byte offsets (weights region, as R4-R9)
constexpr size_t W1M_O = 0;        // ew1 padded [256][32] f16 (k>=9 zero), main
constexpr size_t W1R_O = 16384;    // residual
constexpr size_t E2M_O = 32768;    // ew2 [128][256]
constexpr size_t E2R_O = 98304;
constexpr size_t E3M_O = 163840;   // ew3 [64][128]
constexpr size_t E3R_O = 180224;
constexpr size_t CBM_O = 196608;   // codebook [1024][64]
constexpr size_t CBR_O = 327680;
constexpr size_t D1P_O = 458752;   // dw1 [128][64] plain
constexpr size_t D2P_O = 475136;   // dw2 [256][128] plain
constexpr size_t D3P_O = 540672;   // dw3 padded [16][256] plain
constexpr size_t CN_O  = 548864;   // cn [1024] f32
// ---- small outputs (no big intermediates in this design)
constexpr size_t IDX_O = 589824;             // idx [N] i32 (1 MB)
constexpr size_t ESP_O = IDX_O + 1048576;    // es partials [8192] f32
constexpr size_t HP_O  = ESP_O + 32768;      // hist partials [64][1024] i32

__device__ __forceinline__ void split2(float v, _Float16& hi, _Float16& lo) {
  hi = (_Float16)v;
  lo = (_Float16)(v - (float)hi);
}

// =====================================================================
__global__ void prep_kernel(
    const float* __restrict__ ew1, const float* __restrict__ ew2,
    const float* __restrict__ ew3, const float* __restrict__ cb,
    const float* __restrict__ dw1, const float* __restrict__ dw2,
    const float* __restrict__ dw3, char* __restrict__ wsb) {
  _Float16* w1m = (_Float16*)(wsb + W1M_O);
  _Float16* w1r = (_Float16*)(wsb + W1R_O);
  _Float16* e2m = (_Float16*)(wsb + E2M_O);
  _Float16* e2r = (_Float16*)(wsb + E2R_O);
  _Float16* e3m = (_Float16*)(wsb + E3M_O);
  _Float16* e3r = (_Float16*)(wsb + E3R_O);
  _Float16* cbm = (_Float16*)(wsb + CBM_O);
  _Float16* cbr = (_Float16*)(wsb + CBR_O);
  _Float16* d1p = (_Float16*)(wsb + D1P_O);
  _Float16* d2p = (_Float16*)(wsb + D2P_O);
  _Float16* d3p = (_Float16*)(wsb + D3P_O);
  float* cn = (float*)(wsb + CN_O);

  const int gid = blockIdx.x * 256 + threadIdx.x;
  const int stride = gridDim.x * 256;
  for (int e = gid; e < 256 * 32; e += stride) {
    int n = e >> 5, k = e & 31;
    float v = (k < 9) ? ew1[n * 9 + k] : 0.f;
    split2(v, w1m[e], w1r[e]);
  }
  for (int e = gid; e < 128 * 256; e += stride) split2(ew2[e], e2m[e], e2r[e]);
  for (int e = gid; e < 64 * 128; e += stride) split2(ew3[e], e3m[e], e3r[e]);
  for (int e = gid; e < 1024 * 64; e += stride) split2(cb[e], cbm[e], cbr[e]);
  for (int e = gid; e < 128 * 64; e += stride) d1p[e] = (_Float16)dw1[e];
  for (int e = gid; e < 256 * 128; e += stride) d2p[e] = (_Float16)dw2[e];
  for (int e = gid; e < 16 * 256; e += stride) {
    int n = e >> 8, k = e & 255;
    d3p[e] = (n < 9) ? (_Float16)dw3[n * 256 + k] : (_Float16)0.f;
  }
  for (int i = gid; i < 1024; i += stride) {
    float s = 0.f;
    const float* c = cb + (size_t)i * 64;
#pragma unroll 8
    for (int k = 0; k < 64; ++k) s = fmaf(c[k], c[k], s);
    cn[i] = s;
  }
}

// =====================================================================
// Megakernel: 128 rows/block, 4 waves, 2 row-tiles/wave, shared LDS staging.
__global__ __launch_bounds__(256, 3) void vqvae_mega(
    const float* __restrict__ x,
    const float* __restrict__ eb1, const float* __restrict__ eb2,
    const float* __restrict__ eb3, const float* __restrict__ db1,
    const float* __restrict__ db2, const float* __restrict__ db3,
    const float* __restrict__ cb, const char* __restrict__ wsb,
    float* __restrict__ out, int* __restrict__ idx_g, float* __restrict__ esp_g) {
  __shared__ _Float16 LP[20480];
  __shared__ int Bidx[128];

  const int t = threadIdx.x;
  const int lane = t & 63;
  const int w = t >> 6;
  const int m = lane & 15;
  const int q = lane >> 4;
  const int R0 = blockIdx.x * 128;
  const int wr0 = 32 * w;
  _Float16* WPS = LP + 10240 + w * 2560;
  const float* cn_g = (const float*)(wsb + CN_O);

  half8 axm[2] = {{}, {}}, axr[2] = {{}, {}};
#pragma unroll
  for (int rt = 0; rt < 2; ++rt) {
    const int grow = R0 + wr0 + 16 * rt + m;
    if (q == 0) {
#pragma unroll
      for (int j = 0; j < 8; ++j) {
        const float v = x[(size_t)grow * 9 + j];
        const _Float16 hi = (_Float16)v;
        axm[rt][j] = hi;
        axr[rt][j] = (_Float16)(v - (float)hi);
      }
    } else if (q == 1) {
      const float v = x[(size_t)grow * 9 + 8];
      const _Float16 hi = (_Float16)v;
      axm[rt][0] = hi;
      axr[rt][0] = (_Float16)(v - (float)hi);
    }
  }

  // ================= Stage A: enc1 fused with enc2 (staged W2 chunks)
  floatx4 acc2[8][2];
#pragma unroll
  for (int nt = 0; nt < 8; ++nt)
#pragma unroll
    for (int rt = 0; rt < 2; ++rt) acc2[nt][rt] = (floatx4){0.f, 0.f, 0.f, 0.f};

  for (int kc = 0; kc < 8; ++kc) {
    __syncthreads();
    {
      const int p = t >> 7, n = t & 127;
      const char* src = wsb + (p ? E2R_O : E2M_O) + (size_t)n * 512 + kc * 64;
      _Float16* dst = LP + (p ? 5120 : 0) + n * 40;
#pragma unroll
      for (int j = 0; j < 4; ++j)
        *(half8*)(dst + j * 8) = *(const half8*)(src + j * 16);
    }
#pragma unroll
    for (int ntl = 0; ntl < 2; ++ntl) {
      const int f = kc * 32 + ntl * 16 + m;
      const half8 bm = *(const half8*)(wsb + W1M_O + (size_t)f * 64 + q * 16);
      const half8 br = *(const half8*)(wsb + W1R_O + (size_t)f * 64 + q * 16);
      const float bias = eb1[f];
#pragma unroll
      for (int rt = 0; rt < 2; ++rt) {
        floatx4 a = (floatx4){0.f, 0.f, 0.f, 0.f};
        a = MFMA16(axr[rt], bm, a);
        a = MFMA16(axm[rt], br, a);
        a = MFMA16(axm[rt], bm, a);
#pragma unroll
        for (int reg = 0; reg < 4; ++reg) {
          const float v = fmaxf(a[reg] + bias, 0.f);
          const int row = 16 * rt + 4 * q + reg;
          const _Float16 hi = (_Float16)v;
          WPS[row * 40 + ntl * 16 + m] = hi;
          WPS[1280 + row * 40 + ntl * 16 + m] = (_Float16)(v - (float)hi);
        }
      }
    }
    __syncthreads();
    half8 am[2], ar[2];
#pragma unroll
    for (int rt = 0; rt < 2; ++rt) {
      am[rt] = *(const half8*)(WPS + (16 * rt + m) * 40 + q * 8);
      ar[rt] = *(const half8*)(WPS + 1280 + (16 * rt + m) * 40 + q * 8);
    }
#pragma unroll
    for (int nt = 0; nt < 8; ++nt) {
      const half8 bm = *(const half8*)(LP + (nt * 16 + m) * 40 + q * 8);
      const half8 br = *(const half8*)(LP + 5120 + (nt * 16 + m) * 40 + q * 8);
#pragma unroll
      for (int rt = 0; rt < 2; ++rt) {
        acc2[nt][rt] = MFMA16(ar[rt], bm, acc2[nt][rt]);
        acc2[nt][rt] = MFMA16(am[rt], br, acc2[nt][rt]);
        acc2[nt][rt] = MFMA16(am[rt], bm, acc2[nt][rt]);
      }
    }
  }

  // ================= Stage B: enc3 (B direct from L2; H2 via wave scratch)
  floatx4 acc3[4][2];
#pragma unroll
  for (int nt = 0; nt < 4; ++nt)
#pragma unroll
    for (int rt = 0; rt < 2; ++rt) acc3[nt][rt] = (floatx4){0.f, 0.f, 0.f, 0.f};

  for (int ks = 0; ks < 4; ++ks) {
#pragma unroll
    for (int h = 0; h < 2; ++h) {
      const int nt = 2 * ks + h;
      const float bias = eb2[nt * 16 + m];
#pragma unroll
      for (int rt = 0; rt < 2; ++rt) {
#pragma unroll
        for (int reg = 0; reg < 4; ++reg) {
          const float v = fmaxf(acc2[nt][rt][reg] + bias, 0.f);
          const int row = 16 * rt + 4 * q + reg;
          const _Float16 hi = (_Float16)v;
          WPS[row * 40 + h * 16 + m] = hi;
          WPS[1280 + row * 40 + h * 16 + m] = (_Float16)(v - (float)hi);
        }
      }
    }
    half8 am[2], ar[2];
#pragma unroll
    for (int rt = 0; rt < 2; ++rt) {
      am[rt] = *(const half8*)(WPS + (16 * rt + m) * 40 + q * 8);
      ar[rt] = *(const half8*)(WPS + 1280 + (16 * rt + m) * 40 + q * 8);
    }
#pragma unroll
    for (int nt = 0; nt < 4; ++nt) {
      const half8 bm = *(const half8*)(wsb + E3M_O + (size_t)(nt * 16 + m) * 256 + ks * 64 + q * 16);
      const half8 br = *(const half8*)(wsb + E3R_O + (size_t)(nt * 16 + m) * 256 + ks * 64 + q * 16);
#pragma unroll
      for (int rt = 0; rt < 2; ++rt) {
        acc3[nt][rt] = MFMA16(ar[rt], bm, acc3[nt][rt]);
        acc3[nt][rt] = MFMA16(am[rt], br, acc3[nt][rt]);
        acc3[nt][rt] = MFMA16(am[rt], bm, acc3[nt][rt]);
      }
    }
  }

  // ---- Z epilogue -> register fragments (no ||z||^2 needed for argmin)
  half8 zfm[2][2], zfr[2][2];
#pragma unroll
  for (int rt = 0; rt < 2; ++rt) {
#pragma unroll
    for (int nt = 0; nt < 4; ++nt) {
      const float bias = eb3[nt * 16 + m];
#pragma unroll
      for (int reg = 0; reg < 4; ++reg) {
        const float v = acc3[nt][rt][reg] + bias;
        const int row = 4 * q + reg;
        const _Float16 hi = (_Float16)v;
        WPS[row * 72 + nt * 16 + m] = hi;
        WPS[1152 + row * 72 + nt * 16 + m] = (_Float16)(v - (float)hi);
      }
    }
#pragma unroll
    for (int ks2 = 0; ks2 < 2; ++ks2) {
      zfm[rt][ks2] = *(const half8*)(WPS + m * 72 + ks2 * 32 + q * 8);
      zfr[rt][ks2] = *(const half8*)(WPS + 1152 + m * 72 + ks2 * 32 + q * 8);
    }
  }

  // ================= Stage C: VQ argmin (staged CB chunks of 64)
  float bestd[2][4];
  int besti[2][4];
#pragma unroll
  for (int rt = 0; rt < 2; ++rt)
#pragma unroll
    for (int reg = 0; reg < 4; ++reg) { bestd[rt][reg] = 3.4e38f; besti[rt][reg] = 0; }

  for (int cc = 0; cc < 16; ++cc) {
    __syncthreads();
    {
      const int p = t >> 7, e = t & 127;
      const int n = e >> 1, hh = e & 1;
      const char* src = wsb + (p ? CBR_O : CBM_O) + (size_t)(cc * 64 + n) * 128 + hh * 64;
      _Float16* dst = LP + (p ? 4608 : 0) + n * 72 + hh * 32;
#pragma unroll
      for (int j = 0; j < 4; ++j)
        *(half8*)(dst + j * 8) = *(const half8*)(src + j * 16);
    }
    __syncthreads();
    floatx4 accd[4][2];
#pragma unroll
    for (int nt = 0; nt < 4; ++nt)
#pragma unroll
      for (int rt = 0; rt < 2; ++rt) accd[nt][rt] = (floatx4){0.f, 0.f, 0.f, 0.f};
#pragma unroll
    for (int nt = 0; nt < 4; ++nt) {
#pragma unroll
      for (int ks2 = 0; ks2 < 2; ++ks2) {
        const half8 bm = *(const half8*)(LP + (nt * 16 + m) * 72 + ks2 * 32 + q * 8);
        const half8 br = *(const half8*)(LP + 4608 + (nt * 16 + m) * 72 + ks2 * 32 + q * 8);
#pragma unroll
        for (int rt = 0; rt < 2; ++rt) {
          accd[nt][rt] = MFMA16(zfr[rt][ks2], bm, accd[nt][rt]);
          accd[nt][rt] = MFMA16(zfm[rt][ks2], br, accd[nt][rt]);
          accd[nt][rt] = MFMA16(zfm[rt][ks2], bm, accd[nt][rt]);
        }
      }
    }
#pragma unroll
    for (int nt = 0; nt < 4; ++nt) {
      const int code = cc * 64 + nt * 16 + m;
      const float cnv = cn_g[code];  // ||z||^2 constant per row -> order-preserving
#pragma unroll
      for (int rt = 0; rt < 2; ++rt) {
#pragma unroll
        for (int reg = 0; reg < 4; ++reg) {
          const float d = cnv - 2.f * accd[nt][rt][reg];
          if (d < bestd[rt][reg]) { bestd[rt][reg] = d; besti[rt][reg] = code; }
        }
      }
    }
  }
#pragma unroll
  for (int rt = 0; rt < 2; ++rt) {
#pragma unroll
    for (int reg = 0; reg < 4; ++reg) {
#pragma unroll
      for (int off = 1; off < 16; off <<= 1) {
        const float od = __shfl_xor(bestd[rt][reg], off, 16);
        const int oi = __shfl_xor(besti[rt][reg], off, 16);
        if (od < bestd[rt][reg] || (od == bestd[rt][reg] && oi < besti[rt][reg])) {
          bestd[rt][reg] = od; besti[rt][reg] = oi;
        }
      }
    }
  }
  if (m == 0) {
#pragma unroll
    for (int rt = 0; rt < 2; ++rt)
#pragma unroll
      for (int reg = 0; reg < 4; ++reg) {
        const int row = wr0 + 16 * rt + 4 * q + reg;
        Bidx[row] = besti[rt][reg];        // same-wave LDS use only
        idx_g[R0 + row] = besti[rt][reg];  // plain store; hist kernel follows
      }
  }

  // ---- z_q (straight-through, reference rounding) + per-wave e_latent partial
  half8 zq[2][2];
  float es = 0.f;
#pragma unroll
  for (int rt = 0; rt < 2; ++rt) {
    const int bi = Bidx[wr0 + 16 * rt + m];
#pragma unroll
    for (int ks2 = 0; ks2 < 2; ++ks2) {
      const float* cp = cb + (size_t)bi * 64 + ks2 * 32 + q * 8;
      const float4 c0 = *(const float4*)cp;
      const float4 c1 = *(const float4*)(cp + 4);
      float cv[8] = {c0.x, c0.y, c0.z, c0.w, c1.x, c1.y, c1.z, c1.w};
#pragma unroll
      for (int j = 0; j < 8; ++j) {
        const float z = (float)zfm[rt][ks2][j] + (float)zfr[rt][ks2][j];
        const float d = cv[j] - z;
        es = fmaf(d, d, es);
        zq[rt][ks2][j] = (_Float16)(z + d);
      }
    }
  }
#pragma unroll
  for (int off = 1; off < 64; off <<= 1) es += __shfl_xor(es, off, 64);
  if (lane == 0) esp_g[blockIdx.x * 4 + w] = es;  // no atomic

  // ================= Stage D: dec1 (plain fp16, B direct)
  floatx4 accH[8][2];
#pragma unroll
  for (int nt = 0; nt < 8; ++nt)
#pragma unroll
    for (int rt = 0; rt < 2; ++rt) accH[nt][rt] = (floatx4){0.f, 0.f, 0.f, 0.f};
#pragma unroll
  for (int nt = 0; nt < 8; ++nt) {
#pragma unroll
    for (int ks2 = 0; ks2 < 2; ++ks2) {
      const half8 b = *(const half8*)(wsb + D1P_O + (size_t)(nt * 16 + m) * 128 + ks2 * 64 + q * 16);
#pragma unroll
      for (int rt = 0; rt < 2; ++rt) accH[nt][rt] = MFMA16(zq[rt][ks2], b, accH[nt][rt]);
    }
  }
  half8 h3f[2][4];
  for (int ks = 0; ks < 4; ++ks) {
#pragma unroll
    for (int h = 0; h < 2; ++h) {
      const int nt = 2 * ks + h;
      const float bias = db1[nt * 16 + m];
#pragma unroll
      for (int rt = 0; rt < 2; ++rt)
#pragma unroll
        for (int reg = 0; reg < 4; ++reg) {
          const float v = fmaxf(accH[nt][rt][reg] + bias, 0.f);
          WPS[(16 * rt + 4 * q + reg) * 40 + h * 16 + m] = (_Float16)v;
        }
    }
#pragma unroll
    for (int rt = 0; rt < 2; ++rt)
      h3f[rt][ks] = *(const half8*)(WPS + (16 * rt + m) * 40 + q * 8);
  }

  // ================= Stage E: dec2 (staged WD2 chunks) fused with dec3
  floatx4 accO[2] = {(floatx4){0.f, 0.f, 0.f, 0.f}, (floatx4){0.f, 0.f, 0.f, 0.f}};
  for (int jc = 0; jc < 4; ++jc) {
    __syncthreads();
    {
      const int n = t >> 2, jj = t & 3;
      const char* src = wsb + D2P_O + (size_t)(jc * 64 + n) * 256 + jj * 64;
      _Float16* dst = LP + n * 136 + jj * 32;
#pragma unroll
      for (int j = 0; j < 4; ++j)
        *(half8*)(dst + j * 8) = *(const half8*)(src + j * 16);
    }
    __syncthreads();
    floatx4 accD2[4][2];
#pragma unroll
    for (int nt = 0; nt < 4; ++nt)
#pragma unroll
      for (int rt = 0; rt < 2; ++rt) accD2[nt][rt] = (floatx4){0.f, 0.f, 0.f, 0.f};
#pragma unroll
    for (int nt = 0; nt < 4; ++nt) {
#pragma unroll
      for (int ks = 0; ks < 4; ++ks) {
        const half8 b = *(const half8*)(LP + (nt * 16 + m) * 136 + ks * 32 + q * 8);
#pragma unroll
        for (int rt = 0; rt < 2; ++rt) accD2[nt][rt] = MFMA16(h3f[rt][ks], b, accD2[nt][rt]);
      }
    }
    half8 b3[2];
#pragma unroll
    for (int ks2 = 0; ks2 < 2; ++ks2)
      b3[ks2] = *(const half8*)(wsb + D3P_O + (size_t)m * 512 + jc * 128 + ks2 * 64 + q * 16);
#pragma unroll
    for (int rt = 0; rt < 2; ++rt) {
#pragma unroll
      for (int nt = 0; nt < 4; ++nt) {
        const float bias = db2[jc * 64 + nt * 16 + m];
#pragma unroll
        for (int reg = 0; reg < 4; ++reg) {
          const float v = fmaxf(accD2[nt][rt][reg] + bias, 0.f);
          WPS[(4 * q + reg) * 72 + nt * 16 + m] = (_Float16)v;
        }
      }
#pragma unroll
      for (int ks2 = 0; ks2 < 2; ++ks2) {
        const half8 am = *(const half8*)(WPS + m * 72 + ks2 * 32 + q * 8);
        accO[rt] = MFMA16(am, b3[ks2], accO[rt]);
      }
    }
  }
  if (m < 9) {
    const float bias = db3[m];
#pragma unroll
    for (int rt = 0; rt < 2; ++rt)
#pragma unroll
      for (int reg = 0; reg < 4; ++reg) {
        const size_t r = (size_t)(R0 + wr0 + 16 * rt + 4 * q + reg);
        out[r * 9 + m] = accO[rt][reg] + bias;
      }
  }
}

// =====================================================================
__global__ __launch_bounds__(256) void hist_kernel(
    const int* __restrict__ idx_g, int* __restrict__ hp) {
  __shared__ int lh[1024];
  const int t = threadIdx.x;
#pragma unroll
  for (int i = 0; i < 4; ++i) lh[t * 4 + i] = 0;
  __syncthreads();
  for (int i = t; i < 4096; i += 256)
    atomicAdd(&lh[idx_g[blockIdx.x * 4096 + i]], 1);  // LDS atomic only
  __syncthreads();
  int* part = hp + blockIdx.x * 1024;
#pragma unroll
  for (int i = 0; i < 4; ++i) part[t * 4 + i] = lh[t * 4 + i];
}

// =====================================================================
__global__ __launch_bounds__(1024) void finalize_kernel(
    const int* __restrict__ hp, const float* __restrict__ esp,
    float* __restrict__ out2) {
  __shared__ double red[1024];
  __shared__ float rede[1024];
  const int t = threadIdx.x;
  int h = 0;
#pragma unroll 8
  for (int p = 0; p < 64; ++p) h += hp[p * 1024 + t];
  const float pr = (float)h * (1.0f / (float)kN);
  red[t] = (double)(pr * logf(pr + 1e-10f));
  float es = 0.f;
#pragma unroll
  for (int i = 0; i < 8; ++i) es += esp[i * 1024 + t];
  rede[t] = es;
  __syncthreads();
  for (int s = 512; s > 0; s >>= 1) {
    if (t < s) { red[t] += red[t + s]; rede[t] += rede[t + s]; }
    __syncthreads();
  }
  if (t == 0) {
    out2[0] = 1.25f * (rede[0] * (1.0f / ((float)kN * 64.0f)));
    out2[1] = expf((float)(-red[0]));
  }
}

}  // namespace

extern "C" void kernel_launch(void* const* d_in, const int* in_sizes, int n_in,
                              void* d_out, int out_size, void* d_ws, size_t ws_size,
                              hipStream_t stream) {
  const float* x   = (const float*)d_in[0];
  const float* ew1 = (const float*)d_in[1];
  const float* eb1 = (const float*)d_in[2];
  const float* ew2 = (const float*)d_in[3];
  const float* eb2 = (const float*)d_in[4];
  const float* ew3 = (const float*)d_in[5];
  const float* eb3 = (const float*)d_in[6];
  const float* dw1 = (const float*)d_in[7];
  const float* db1 = (const float*)d_in[8];
  const float* dw2 = (const float*)d_in[9];
  const float* db2 = (const float*)d_in[10];
  const float* dw3 = (const float*)d_in[11];
  const float* db3 = (const float*)d_in[12];
  const float* cb  = (const float*)d_in[13];
  float* out = (float*)d_out;
  char* wsb = (char*)d_ws;

  int* idx_g = (int*)(wsb + IDX_O);
  float* esp = (float*)(wsb + ESP_O);
  int* hp = (int*)(wsb + HP_O);

  prep_kernel<<<128, 256, 0, stream>>>(ew1, ew2, ew3, cb, dw1, dw2, dw3, wsb);
  vqvae_mega<<<kN / 128, 256, 0, stream>>>(x, eb1, eb2, eb3, db1, db2, db3, cb,
                                           wsb, out, idx_g, esp);
  hist_kernel<<<64, 256, 0, stream>>>(idx_g, hp);
  finalize_kernel<<<1, 1024, 0, stream>>>(hp, esp, out + (size_t)kN * 9);
}